// Round 4
// baseline (1133.733 us; speedup 1.0000x reference)
//
#include <hip/hip_runtime.h>
#include <hip/hip_bf16.h>
#include <math.h>

#define N_   2048
#define SEQ_ 128
#define E_   512
#define R_   128
#define NR_  (N_ * R_)

typedef __attribute__((ext_vector_type(8))) short short8;
typedef __attribute__((ext_vector_type(4))) float f32x4;
typedef __attribute__((ext_vector_type(16))) float f32x16;

typedef __attribute__((address_space(3))) void lds_t;
typedef __attribute__((address_space(1))) const void glb_t;

__device__ __forceinline__ void async16(void* l, const void* g) {
    // 16B per lane: LDS dest = uniform base + lane*16; global src per-lane.
    __builtin_amdgcn_global_load_lds((glb_t*)g, (lds_t*)l, 16, 0, 0);
}

__device__ __forceinline__ ushort f2bf(float f) {
    union { float f; uint u; } v; v.f = f;
    uint r = v.u + 0x7FFFu + ((v.u >> 16) & 1u);   // RNE
    return (ushort)(r >> 16);
}
__device__ __forceinline__ float fast_tanhf(float x) {
    float ax = fabsf(x);
    float t = __expf(-2.f * ax);
    float r = (1.f - t) / (1.f + t);
    return copysignf(r, x);
}
// 8 fp32 -> 8 bf16 (RNE) via packed HW converts
__device__ __forceinline__ short8 cvt8(float4 a, float4 b) {
    union { short8 v; __hip_bfloat162 h[4]; } t;
    t.h[0] = __float22bfloat162_rn(make_float2(a.x, a.y));
    t.h[1] = __float22bfloat162_rn(make_float2(a.z, a.w));
    t.h[2] = __float22bfloat162_rn(make_float2(b.x, b.y));
    t.h[3] = __float22bfloat162_rn(make_float2(b.z, b.w));
    return t.v;
}

// ---- prep: W^T bf16: three ExR -> [128][512]; two RxR -> [128][128] ----
__global__ void prep_kernel(const float* __restrict__ W1p, const float* __restrict__ W1n,
                            const float* __restrict__ Wa,  const float* __restrict__ W2p,
                            const float* __restrict__ W2n, ushort* __restrict__ WT)
{
    int idx = blockIdx.x * 256 + threadIdx.x;      // 0..229375
    if (idx < 196608) {
        int m = idx >> 16;
        int o = idx & 65535;
        int r = o >> 9, e = o & 511;
        const float* src = (m == 0) ? W1p : (m == 1) ? W1n : Wa;
        WT[idx] = f2bf(src[e * R_ + r]);
    } else if (idx < 229376) {
        int o = idx - 196608;
        int m = o >> 14;
        int p = o & 16383;
        int r = p >> 7, e = p & 127;
        const float* src = (m == 0) ? W2p : W2n;
        WT[idx] = f2bf(src[e * R_ + r]);
    }
}

// One block per (n, half): 512 threads, 8 waves. Wave = (m-tile 32 t, n-tile 32 r, 3 sets).
// 32x32x16 MFMA; X: global->reg->A-frag (no LDS). W: 24KB chunk-staged, pair-row XOR
// swizzle (conflict-free b128). Phase 2: 16x16 MFMA, W2 staged in two 16KB k-halves.
__global__ __launch_bounds__(512, 4)
void mlp_mfma_kernel(const int* __restrict__ C, const float* __restrict__ L,
                     const float* __restrict__ Pw, const float* __restrict__ Nw,
                     const float* __restrict__ b1p, const float* __restrict__ b2p,
                     const float* __restrict__ b1n, const float* __restrict__ b2n,
                     const float* __restrict__ ba,  const ushort* __restrict__ WT,
                     float* __restrict__ pp, float* __restrict__ nn,
                     float* __restrict__ aa)     // each [2][N][R] partials
{
    // phase1: sW [3 sets][64 pair-rows][64] = 24KB at lds[0..12288)
    // phase2: sW2h [128][64] = 16KB at lds[0..8192); sH1 [64][128] = 16KB at lds[8192..16384)
    __shared__ __align__(16) ushort lds[16384];    // 32 KB
    __shared__ float sRed[4][128];
    __shared__ float sPm[64], sNm[64];

    const ushort* W2pT = WT + 196608;
    const ushort* W2nT = WT + 212992;

    const int bid = blockIdx.x;
    const int n = bid >> 1, hf = bid & 1;
    const int tid = threadIdx.x;
    const int w = tid >> 6, l = tid & 63;
    const int l31 = l & 31, lh = l >> 5;      // 32-wide frag indexing (phase 1)
    const int c = l & 15, q = l >> 4;         // 16-wide frag indexing (phase 2)
    const int m = w >> 2, n4 = w & 3;         // wave cell: m-tile, n-tile

    if (tid < 64) {
        int tg = hf * 64 + tid;
        int c0 = C[2 * n], c1 = C[2 * n + 1];
        bool in = (tg >= c0) && (tg <= c1);
        sPm[tid] = in ? Pw[n * SEQ_ + tg] : 0.f;
        sNm[tid] = in ? 0.f : Nw[n * SEQ_ + tg];
    }

    f32x16 aP = 0.f, aN = 0.f, aA = 0.f;

    // This lane's A-row of L (row t = m*32 + l31), k sub-offset lh*8.
    const float* Lrow = L + ((size_t)(n * SEQ_ + hf * 64 + m * 32 + l31)) * E_;

    // Phase-1 B-read constants: r-col = n4*32 + l31, pair-row RB, slot XOR.
    const int rB = n4 * 32 + l31;
    const int RB = rB >> 1;
    const int ub = ((rB & 1) * 4 + lh) ^ (RB & 7);     // bit2=r&1, bit1=kstep(^below), bit0=lh
    const int oB0 = RB * 64 + ub * 8;                  // kstep 0
    const int oB1 = RB * 64 + (ub ^ 2) * 8;            // kstep 1

    for (int ch = 0; ch < 16; ++ch) {
        const int kb = ch * 32;
        // X loads first (HBM latency hides under DMA + converts)
        const float* px = Lrow + kb + lh * 8;
        float4 x0a = *(const float4*)px;
        float4 x0b = *(const float4*)(px + 4);
        float4 x1a = *(const float4*)(px + 16);
        float4 x1b = *(const float4*)(px + 20);
        // W DMA: 3 sets x 64 pair-rows x 64 elems, 24 instrs/block (3/wave).
        // Slot p of pair-row R holds source (row 2R+(u>>2), seg u&3), u = p^(R&7).
#pragma unroll
        for (int j = 0; j < 3; ++j) {
            int gi = j * 8 + w;                 // 0..23
            int s = gi >> 3, g8 = gi & 7;
            int R = g8 * 8 + (l >> 3);
            int u = (l & 7) ^ (R & 7);
            int r = 2 * R + (u >> 2);
            int tseg = u & 3;
            async16(&lds[(s * 64 + g8 * 8) * 64], WT + s * 65536 + r * E_ + kb + tseg * 8);
        }
        short8 a0 = cvt8(x0a, x0b);   // k = kb + lh*8 + 0..7       (kstep 0)
        short8 a1 = cvt8(x1a, x1b);   // k = kb + 16 + lh*8 + 0..7  (kstep 1)
        __syncthreads();
        {
            short8 bP0 = *(const short8*)&lds[oB0];
            short8 bN0 = *(const short8*)&lds[4096 + oB0];
            short8 bA0 = *(const short8*)&lds[8192 + oB0];
            aP = __builtin_amdgcn_mfma_f32_32x32x16_bf16(a0, bP0, aP, 0, 0, 0);
            aN = __builtin_amdgcn_mfma_f32_32x32x16_bf16(a0, bN0, aN, 0, 0, 0);
            aA = __builtin_amdgcn_mfma_f32_32x32x16_bf16(a0, bA0, aA, 0, 0, 0);
            short8 bP1 = *(const short8*)&lds[oB1];
            short8 bN1 = *(const short8*)&lds[4096 + oB1];
            short8 bA1 = *(const short8*)&lds[8192 + oB1];
            aP = __builtin_amdgcn_mfma_f32_32x32x16_bf16(a1, bP1, aP, 0, 0, 0);
            aN = __builtin_amdgcn_mfma_f32_32x32x16_bf16(a1, bN1, aN, 0, 0, 0);
            aA = __builtin_amdgcn_mfma_f32_32x32x16_bf16(a1, bA1, aA, 0, 0, 0);
        }
        __syncthreads();
    }

    // ---- A-set epilogue ----
    // 32x32 C-layout: col = l31 (= r), row t = m*32 + (reg&3) + 8*(reg>>2) + 4*lh
    {
        float bar_ = ba[rB];
        float s = 0.f;
#pragma unroll
        for (int reg = 0; reg < 16; ++reg) {
            int t = m * 32 + (reg & 3) + 8 * (reg >> 2) + 4 * lh;
            float mv = sPm[t] + sNm[t];
            s += fast_tanhf(fmaf(mv, aA[reg], bar_));
        }
        s += __shfl_xor(s, 32);
        if (l < 32) sRed[m][rB] = s;
    }
    __syncthreads();
    if (tid < 128)
        aa[hf * NR_ + n * R_ + tid] = (sRed[0][tid] + sRed[1][tid]) * (1.f / SEQ_);

    // ---- P then N ----
#pragma unroll
    for (int ps = 0; ps < 2; ++ps) {
        const f32x16 acc1 = ps ? aN : aP;
        const float* sM  = ps ? sNm : sPm;
        const float* b1  = ps ? b1n : b1p;
        const float* b2  = ps ? b2n : b2p;
        const ushort* W2T = ps ? W2nT : W2pT;
        float* outp = ps ? nn : pp;

        // h1 -> sH1 [64 t][128 r], 16B segs stored at (r>>3)^(t&7). Safe: all prior
        // readers of lds passed a barrier (chunk-loop tail / ps=0 epilogue barrier).
        {
            float b1r = b1[rB];
            int rlo = rB & 7, rseg = rB >> 3;
#pragma unroll
            for (int reg = 0; reg < 16; ++reg) {
                int t = m * 32 + (reg & 3) + 8 * (reg >> 2) + 4 * lh;
                float h = fast_tanhf(fmaf(sM[t], acc1[reg], b1r));
                lds[8192 + t * 128 + ((rseg ^ (t & 7)) * 8) + rlo] = f2bf(h);
            }
        }
        // W2 k-half 0 DMA: [128 r2][64 k] at lds[0..8192)
#pragma unroll
        for (int j = 0; j < 2; ++j) {
            int gi = j * 8 + w;                 // 0..15
            int row = gi * 8 + (l >> 3);
            int tseg = (l & 7) ^ (row & 7);
            async16(&lds[gi * 512], W2T + row * 128 + tseg * 8);
        }
        __syncthreads();

        f32x4 acc2[4];
#pragma unroll
        for (int nt = 0; nt < 4; ++nt) acc2[nt] = 0.f;

        const int arow = n4 * 16 + c;           // wave's t-group: (w&3)*16 + c
        const int r2base = m * 64;              // wave's r2-half
#pragma unroll
        for (int kh = 0; kh < 2; ++kh) {
            if (kh) {
                __syncthreads();                // kh0 reads of sW2h done
#pragma unroll
                for (int j = 0; j < 2; ++j) {
                    int gi = j * 8 + w;
                    int row = gi * 8 + (l >> 3);
                    int tseg = (l & 7) ^ (row & 7);
                    async16(&lds[gi * 512], W2T + row * 128 + 64 + tseg * 8);
                }
                __syncthreads();
            }
#pragma unroll
            for (int k2 = 0; k2 < 2; ++k2) {
                int sg = kh * 8 + k2 * 4 + q;   // 4-bit seg; XOR touches low 3 bits only
                short8 af = *(const short8*)&lds[8192 + arow * 128 + ((sg ^ (c & 7)) * 8)];
#pragma unroll
                for (int nt = 0; nt < 4; ++nt) {
                    int r2 = r2base + nt * 16 + c;
                    short8 bf_ = *(const short8*)&lds[r2 * 64 + (((k2 * 4 + q) ^ (c & 7)) * 8)];
                    acc2[nt] = __builtin_amdgcn_mfma_f32_16x16x32_bf16(af, bf_, acc2[nt], 0, 0, 0);
                }
            }
        }
#pragma unroll
        for (int nt = 0; nt < 4; ++nt) {
            int r2 = r2base + nt * 16 + c;
            float b2r = b2[r2];
            float s = 0.f;
#pragma unroll
            for (int i = 0; i < 4; ++i)
                s += fast_tanhf(acc2[nt][i] + b2r);
            s += __shfl_xor(s, 16);
            s += __shfl_xor(s, 32);
            if (q == 0) sRed[n4][r2] = s;       // one writer per (t-group, r2)
        }
        __syncthreads();
        if (tid < 128)
            outp[hf * NR_ + n * R_ + tid] =
                (sRed[0][tid] + sRed[1][tid] + sRed[2][tid] + sRed[3][tid]) * (1.f / SEQ_);
    }
}

// ---- combine ff halves -> d_out ----
__global__ __launch_bounds__(256)
void ffcomb_kernel(const float* __restrict__ aa, float* __restrict__ out)
{
    int i = (blockIdx.x * 256 + threadIdx.x) * 4;
    float4 a0 = *(const float4*)(aa + i);
    float4 a1 = *(const float4*)(aa + NR_ + i);
    float4 o; o.x = a0.x + a1.x; o.y = a0.y + a1.y; o.z = a0.z + a1.z; o.w = a0.w + a1.w;
    *(float4*)(out + i) = o;
}

// ---- pairwise exp(-dist): 64i x 32j tile per block, per-block partials (no atomics) ----
__global__ __launch_bounds__(256, 2)
void sim_kernel(const float* __restrict__ pp, const float* __restrict__ nn,
                float* __restrict__ simP, float* __restrict__ simN)
{
    __shared__ __align__(16) float sPi[64][133];
    __shared__ __align__(16) float sPj[32][133];
    __shared__ __align__(16) float sNj[32][133];

    const int jb = blockIdx.x;   // 0..63
    const int ib = blockIdx.y;   // 0..31
    const int tid = threadIdx.x;

#pragma unroll
    for (int it = 0; it < 8; ++it) {
        int idx = it * 256 + tid;
        int row = idx >> 5, seg = idx & 31;
        int g = (ib * 64 + row) * R_ + seg * 4;
        float4 a = *(const float4*)(pp + g);
        float4 b = *(const float4*)(pp + NR_ + g);
        a.x += b.x; a.y += b.y; a.z += b.z; a.w += b.w;
        *(float4*)&sPi[row][seg * 4] = a;
    }
#pragma unroll
    for (int it = 0; it < 4; ++it) {
        int idx = it * 256 + tid;
        int row = idx >> 5, seg = idx & 31;
        int g = (jb * 32 + row) * R_ + seg * 4;
        float4 a = *(const float4*)(pp + g);
        float4 b = *(const float4*)(pp + NR_ + g);
        a.x += b.x; a.y += b.y; a.z += b.z; a.w += b.w;
        *(float4*)&sPj[row][seg * 4] = a;
        float4 u = *(const float4*)(nn + g);
        float4 v = *(const float4*)(nn + NR_ + g);
        u.x += v.x; u.y += v.y; u.z += v.z; u.w += v.w;
        *(float4*)&sNj[row][seg * 4] = u;
    }
    __syncthreads();

    const int ty = tid >> 4, tx = tid & 15;
    float d2p[4][2] = {}, d2n[4][2] = {};

    for (int rr = 0; rr < R_; rr += 4) {
        float4 xi[4], pj[2], nj[2];
#pragma unroll
        for (int a = 0; a < 4; ++a) xi[a] = *(const float4*)&sPi[ty * 4 + a][rr];
#pragma unroll
        for (int b = 0; b < 2; ++b) {
            pj[b] = *(const float4*)&sPj[tx * 2 + b][rr];
            nj[b] = *(const float4*)&sNj[tx * 2 + b][rr];
        }
#pragma unroll
        for (int a = 0; a < 4; ++a)
#pragma unroll
            for (int b = 0; b < 2; ++b) {
                float dx;
                dx = xi[a].x - pj[b].x; d2p[a][b] = fmaf(dx, dx, d2p[a][b]);
                dx = xi[a].y - pj[b].y; d2p[a][b] = fmaf(dx, dx, d2p[a][b]);
                dx = xi[a].z - pj[b].z; d2p[a][b] = fmaf(dx, dx, d2p[a][b]);
                dx = xi[a].w - pj[b].w; d2p[a][b] = fmaf(dx, dx, d2p[a][b]);
                dx = xi[a].x - nj[b].x; d2n[a][b] = fmaf(dx, dx, d2n[a][b]);
                dx = xi[a].y - nj[b].y; d2n[a][b] = fmaf(dx, dx, d2n[a][b]);
                dx = xi[a].z - nj[b].z; d2n[a][b] = fmaf(dx, dx, d2n[a][b]);
                dx = xi[a].w - nj[b].w; d2n[a][b] = fmaf(dx, dx, d2n[a][b]);
            }
    }

    float sp = 0.f, sn = 0.f;
#pragma unroll
    for (int a = 0; a < 4; ++a)
#pragma unroll
        for (int b = 0; b < 2; ++b) {
            sp += __expf(-sqrtf(d2p[a][b]));
            sn += __expf(-sqrtf(d2n[a][b]));
        }

#pragma unroll
    for (int off = 32; off; off >>= 1) {
        sp += __shfl_down(sp, off);
        sn += __shfl_down(sn, off);
    }
    __shared__ float redP[4], redN[4];
    const int wave = tid >> 6, lane = tid & 63;
    if (lane == 0) { redP[wave] = sp; redN[wave] = sn; }
    __syncthreads();
    if (tid == 0) {
        int bidl = ib * 64 + jb;
        simP[bidl] = redP[0] + redP[1] + redP[2] + redP[3];
        simN[bidl] = redN[0] + redN[1] + redN[2] + redN[3];
    }
}

__global__ __launch_bounds__(256)
void finalize_kernel(const float* __restrict__ simP, const float* __restrict__ simN,
                     float* __restrict__ out)
{
    const int tid = threadIdx.x;
    double sp = 0.0, sn = 0.0;
    for (int i = tid; i < 2048; i += 256) { sp += (double)simP[i]; sn += (double)simN[i]; }
    __shared__ double rp[256], rn[256];
    rp[tid] = sp; rn[tid] = sn;
    __syncthreads();
    for (int s = 128; s; s >>= 1) {
        if (tid < s) { rp[tid] += rp[tid + s]; rn[tid] += rn[tid + s]; }
        __syncthreads();
    }
    if (tid == 0) out[NR_] = (float)(-log(rp[0] / rn[0]));
}

extern "C" void kernel_launch(void* const* d_in, const int* in_sizes, int n_in,
                              void* d_out, int out_size, void* d_ws, size_t ws_size,
                              hipStream_t stream)
{
    const int*   C   = (const int*)  d_in[0];
    const float* L   = (const float*)d_in[1];
    const float* Pw  = (const float*)d_in[2];
    const float* Nw  = (const float*)d_in[3];
    const float* W1p = (const float*)d_in[4];
    const float* b1p = (const float*)d_in[5];
    const float* W2p = (const float*)d_in[6];
    const float* b2p = (const float*)d_in[7];
    const float* W1n = (const float*)d_in[8];
    const float* b1n = (const float*)d_in[9];
    const float* W2n = (const float*)d_in[10];
    const float* b2n = (const float*)d_in[11];
    const float* Wa  = (const float*)d_in[12];
    const float* ba  = (const float*)d_in[13];

    float* out = (float*)d_out;
    float* pp  = (float*)d_ws;            // [2][N][R]
    float* nn  = pp + 2 * NR_;            // [2][N][R]
    float* aa  = nn + 2 * NR_;            // [2][N][R]
    float* simP = aa + 2 * NR_;           // [2048]
    float* simN = simP + 2048;            // [2048]
    ushort* WT = (ushort*)((char*)d_ws + 6 * (size_t)NR_ * 4 + 65536);   // 448 KB

    hipLaunchKernelGGL(prep_kernel, dim3(896), dim3(256), 0, stream,
                       W1p, W1n, Wa, W2p, W2n, WT);
    hipLaunchKernelGGL(mlp_mfma_kernel, dim3(2 * N_), dim3(512), 0, stream,
                       C, L, Pw, Nw, b1p, b2p, b1n, b2n, ba, WT, pp, nn, aa);
    hipLaunchKernelGGL(ffcomb_kernel, dim3(NR_ / 1024), dim3(256), 0, stream, aa, out);
    hipLaunchKernelGGL(sim_kernel, dim3(64, 32), dim3(256), 0, stream,
                       pp, nn, simP, simN);
    hipLaunchKernelGGL(finalize_kernel, dim3(1), dim3(256), 0, stream, simP, simN, out);
}